// Round 17
// baseline (210.336 us; speedup 1.0000x reference)
//
#include <hip/hip_runtime.h>
#include <hip/hip_bf16.h>

// Problem constants
#define B_ 4
#define S_ 2048
#define D_ 1024
#define H_ 16
#define HD_ 64
#define M_ 8192           // B*S
#define NEGV -1000000.0f
#define CEXP 0.18033688011112042f   // (1/sqrt(HD)) * log2(e) — folded into Q projection

typedef __attribute__((ext_vector_type(8))) __bf16 bf16x8;
typedef __attribute__((ext_vector_type(4))) float f32x4;
typedef __attribute__((ext_vector_type(16))) float f32x16;

__device__ __forceinline__ f32x4 mfma16(bf16x8 a, bf16x8 b, f32x4 c) {
  return __builtin_amdgcn_mfma_f32_16x16x32_bf16(a, b, c, 0, 0, 0);
}
__device__ __forceinline__ f32x16 mfma32(bf16x8 a, bf16x8 b, f32x16 c) {
  return __builtin_amdgcn_mfma_f32_32x32x16_bf16(a, b, c, 0, 0, 0);
}

// raw v_exp_f32 (exp2f without -ffast-math is a guarded libm sequence)
#if __has_builtin(__builtin_amdgcn_exp2f)
__device__ __forceinline__ float exp2_hw(float x) { return __builtin_amdgcn_exp2f(x); }
#else
__device__ __forceinline__ float exp2_hw(float x) {
  float r;
  asm volatile("v_exp_f32 %0, %1" : "=v"(r) : "v"(x));
  return r;
}
#endif

// Branchless RNE fp32->bf16 (exact for all finite values; no NaNs in this pipeline).
__device__ __forceinline__ unsigned bf16rz(float x) {
  unsigned u = __float_as_uint(x);
  return (u + 0x7FFFu + ((u >> 16) & 1u)) >> 16;
}
// pack two floats -> bf16x2 word (lo = a, hi = b)
__device__ __forceinline__ unsigned pk2bf(float a, float b) {
  unsigned ua = __float_as_uint(a), ub = __float_as_uint(b);
  ua = ua + 0x7FFFu + ((ua >> 16) & 1u);
  ub = ub + 0x7FFFu + ((ub >> 16) & 1u);
  return (ua >> 16) | (ub & 0xFFFF0000u);
}

// async global->LDS, 16B per lane. LDS dest is wave-uniform base (HW adds lane*16).
__device__ __forceinline__ void gld_lds16(const __hip_bfloat16* g, __hip_bfloat16* l) {
  __builtin_amdgcn_global_load_lds(
      (const __attribute__((address_space(1))) void*)g,
      (__attribute__((address_space(3))) void*)l, 16, 0, 0);
}

// ---------------- fp32 -> bf16 convert, all three X tensors in one launch -------------
__global__ __launch_bounds__(256) void convert_x3(const float* __restrict__ Xq,
                                                  const float* __restrict__ Xk,
                                                  const float* __restrict__ Xv,
                                                  __hip_bfloat16* __restrict__ Yq,
                                                  __hip_bfloat16* __restrict__ Yk,
                                                  __hip_bfloat16* __restrict__ Yv,
                                                  int n4, const int* __restrict__ vl) {
  const int z = blockIdx.y;
  const float* X = (z == 0) ? Xq : (z == 1) ? Xk : Xv;
  __hip_bfloat16* Y = (z == 0) ? Yq : (z == 1) ? Yk : Yv;
  int i = blockIdx.x * blockDim.x + threadIdx.x;
  if (i >= n4) return;
  if (z) {
    int gm = i >> 8;  // 256 float4 per 1024-wide row
    int vlen = vl[gm >> 11];
    if (vlen > 0 && (gm & 2047) >= ((vlen + 63) & ~63)) return;
  }
  float4 v = reinterpret_cast<const float4*>(X)[i];
  uint2 o;
  o.x = pk2bf(v.x, v.y);
  o.y = pk2bf(v.z, v.w);
  reinterpret_cast<uint2*>(Y)[i] = o;
}

// ---------------- 4x W[1024][1024] fp32 -> W^T bf16 (fused via blockIdx.z) -----------
__global__ __launch_bounds__(256) void convert_wt4(const float* __restrict__ W0,
                                                   const float* __restrict__ W1,
                                                   const float* __restrict__ W2,
                                                   const float* __restrict__ W3,
                                                   __hip_bfloat16* __restrict__ WtBase) {
  const int z = blockIdx.z;
  const float* W = (z == 0) ? W0 : (z == 1) ? W1 : (z == 2) ? W2 : W3;
  __hip_bfloat16* Wt = WtBase + (size_t)z * D_ * D_;
  __shared__ float tile[32][33];
  int c0 = blockIdx.x * 32, r0 = blockIdx.y * 32;
  int tx = threadIdx.x, ty = threadIdx.y;
#pragma unroll
  for (int rr = ty; rr < 32; rr += 8)
    tile[rr][tx] = W[(size_t)(r0 + rr) * D_ + c0 + tx];
  __syncthreads();
#pragma unroll
  for (int rr = ty; rr < 32; rr += 8)
    reinterpret_cast<unsigned short*>(Wt)[(size_t)(c0 + rr) * D_ + r0 + tx] =
        (unsigned short)bf16rz(tile[tx][rr]);
}

// ---------------- Fused Q/K/V projection GEMM (one dispatch, grid.z = 3) --------------
// Inner loop identical to the R9-R16-validated gemm_bt: BK=64, XOR-swizzled LDS (T2),
// double-buffered 2-phase schedule.
__global__ __launch_bounds__(256) void gemm_qkv(const __hip_bfloat16* __restrict__ Aq,
                                                const __hip_bfloat16* __restrict__ Ak,
                                                const __hip_bfloat16* __restrict__ Av,
                                                const __hip_bfloat16* __restrict__ WtBase,
                                                __hip_bfloat16* __restrict__ Qh,
                                                __hip_bfloat16* __restrict__ Kh,
                                                __hip_bfloat16* __restrict__ Vh,
                                                const int* __restrict__ vl) {
  const int z = blockIdx.z;
  const __hip_bfloat16* A = (z == 0) ? Aq : (z == 1) ? Ak : Av;
  const __hip_bfloat16* Bt = WtBase + (size_t)z * D_ * D_;
  __hip_bfloat16* Cout = (z == 0) ? Qh : (z == 1) ? Kh : Vh;
  const float cscale = (z == 0) ? CEXP : 1.0f;
  const int epi = (z == 2) ? 1 : 0;

  int id = blockIdx.y * gridDim.x + blockIdx.x;
  int cpx = (gridDim.x * gridDim.y) >> 3;
  int nid = (id & 7) * cpx + (id >> 3);
  const int m0 = (nid >> 3) * 128, n0 = (nid & 7) * 128;
  if (z) {
    int vlen = vl[m0 >> 11];
    if (vlen > 0 && (m0 & 2047) >= ((vlen + 63) & ~63)) return;
  }
  const int t = threadIdx.x, lane = t & 63, wid = t >> 6;
  const int lc = lane & 15, g = lane >> 4;
  const int srow8 = lane >> 3, sg8 = lane & 7;
  __shared__ __align__(16) __hip_bfloat16 smem[2][2][128 * 64];  // [buf][A/B][tile] 64KB
  f32x4 acc[4][4] = {};
  const int wm = (wid & 1) * 64, wn = (wid >> 1) * 64;

  auto stage = [&](int buf, int k0) {
#pragma unroll
    for (int c = 0; c < 4; ++c) {
      int ci = c * 4 + wid;              // 1KB chunk index (8 rows)
      int row = ci * 8 + srow8;          // this lane's source row
      int sg = sg8 ^ (row & 7);          // inverse-swizzled source granule
      gld_lds16(A + (size_t)(m0 + row) * D_ + k0 + sg * 8, &smem[buf][0][ci * 512]);
      gld_lds16(Bt + (size_t)(n0 + row) * D_ + k0 + sg * 8, &smem[buf][1][ci * 512]);
    }
  };

  stage(0, 0);
  asm volatile("s_waitcnt vmcnt(0)" ::: "memory");
  __syncthreads();
  int cur = 0;

  for (int kt = 0; kt < D_ / 64; ++kt) {
    if (kt + 1 < D_ / 64) stage(cur ^ 1, (kt + 1) * 64);  // prefetch overlaps compute
    const __hip_bfloat16* As = smem[cur][0];
    const __hip_bfloat16* Bs = smem[cur][1];
#pragma unroll
    for (int kh = 0; kh < 2; ++kh) {  // two K=32 halves of the K=64 tile
      bf16x8 af[4], bf[4];
#pragma unroll
      for (int mi = 0; mi < 4; ++mi) {
        int r = wm + mi * 16 + lc;
        af[mi] = *reinterpret_cast<const bf16x8*>(
            As + r * 64 + (((kh * 4 + g) ^ (r & 7)) << 3));
        int rn = wn + mi * 16 + lc;
        bf[mi] = *reinterpret_cast<const bf16x8*>(
            Bs + rn * 64 + (((kh * 4 + g) ^ (rn & 7)) << 3));
      }
#pragma unroll
      for (int mi = 0; mi < 4; ++mi)
#pragma unroll
        for (int ni = 0; ni < 4; ++ni)
          acc[mi][ni] = mfma16(af[mi], bf[ni], acc[mi][ni]);
    }
    asm volatile("s_waitcnt vmcnt(0)" ::: "memory");
    __syncthreads();
    cur ^= 1;
  }

#pragma unroll
  for (int mi = 0; mi < 4; ++mi) {
#pragma unroll
    for (int ni = 0; ni < 4; ++ni) {
#pragma unroll
      for (int i = 0; i < 4; ++i) {
        int gm = m0 + wm + mi * 16 + g * 4 + i;
        int gn = n0 + wn + ni * 16 + lc;
        float val = acc[mi][ni][i] * cscale;
        int b = gm >> 11, s = gm & 2047, h = gn >> 6, d = gn & 63;
        if (epi == 0) {
          reinterpret_cast<unsigned short*>(
              Cout)[(((size_t)(b * H_ + h) * S_ + s) << 6) + d] =
              (unsigned short)bf16rz(val);
        } else {
          reinterpret_cast<unsigned short*>(
              Cout)[(((size_t)(b * H_ + h) * HD_ + d) << 11) + s] =
              (unsigned short)bf16rz(val);
        }
      }
    }
  }
}

// ---------------- GEMM: C[M,N] = A[M,K] * Bt[N,K]^T  (final @ Wo, fp32 out) -----------
template <int EPI>
__global__ __launch_bounds__(256) void gemm_bt(const __hip_bfloat16* __restrict__ A,
                                               const __hip_bfloat16* __restrict__ Bt,
                                               void* __restrict__ Cout,
                                               const int* __restrict__ vskip,
                                               float cscale) {
  int id = blockIdx.y * gridDim.x + blockIdx.x;
  int cpx = (gridDim.x * gridDim.y) >> 3;
  int nid = (id & 7) * cpx + (id >> 3);
  const int m0 = (nid >> 3) * 128, n0 = (nid & 7) * 128;
  if (vskip) {
    int vlen = vskip[m0 >> 11];
    if (vlen > 0 && (m0 & 2047) >= ((vlen + 63) & ~63)) return;
  }
  const int t = threadIdx.x, lane = t & 63, wid = t >> 6;
  const int lc = lane & 15, g = lane >> 4;
  const int srow8 = lane >> 3, sg8 = lane & 7;
  __shared__ __align__(16) __hip_bfloat16 smem[2][2][128 * 64];  // [buf][A/B][tile] 64KB
  f32x4 acc[4][4] = {};
  const int wm = (wid & 1) * 64, wn = (wid >> 1) * 64;

  auto stage = [&](int buf, int k0) {
#pragma unroll
    for (int c = 0; c < 4; ++c) {
      int ci = c * 4 + wid;
      int row = ci * 8 + srow8;
      int sg = sg8 ^ (row & 7);
      gld_lds16(A + (size_t)(m0 + row) * D_ + k0 + sg * 8, &smem[buf][0][ci * 512]);
      gld_lds16(Bt + (size_t)(n0 + row) * D_ + k0 + sg * 8, &smem[buf][1][ci * 512]);
    }
  };

  stage(0, 0);
  asm volatile("s_waitcnt vmcnt(0)" ::: "memory");
  __syncthreads();
  int cur = 0;

  for (int kt = 0; kt < D_ / 64; ++kt) {
    if (kt + 1 < D_ / 64) stage(cur ^ 1, (kt + 1) * 64);
    const __hip_bfloat16* As = smem[cur][0];
    const __hip_bfloat16* Bs = smem[cur][1];
#pragma unroll
    for (int kh = 0; kh < 2; ++kh) {
      bf16x8 af[4], bf[4];
#pragma unroll
      for (int mi = 0; mi < 4; ++mi) {
        int r = wm + mi * 16 + lc;
        af[mi] = *reinterpret_cast<const bf16x8*>(
            As + r * 64 + (((kh * 4 + g) ^ (r & 7)) << 3));
        int rn = wn + mi * 16 + lc;
        bf[mi] = *reinterpret_cast<const bf16x8*>(
            Bs + rn * 64 + (((kh * 4 + g) ^ (rn & 7)) << 3));
      }
#pragma unroll
      for (int mi = 0; mi < 4; ++mi)
#pragma unroll
        for (int ni = 0; ni < 4; ++ni)
          acc[mi][ni] = mfma16(af[mi], bf[ni], acc[mi][ni]);
    }
    asm volatile("s_waitcnt vmcnt(0)" ::: "memory");
    __syncthreads();
    cur ^= 1;
  }

#pragma unroll
  for (int mi = 0; mi < 4; ++mi) {
#pragma unroll
    for (int ni = 0; ni < 4; ++ni) {
#pragma unroll
      for (int i = 0; i < 4; ++i) {
        int gm = m0 + wm + mi * 16 + g * 4 + i;
        int gn = n0 + wn + ni * 16 + lc;
        float val = acc[mi][ni][i] * cscale;
        if constexpr (EPI == 0) {
          int b = gm >> 11, s = gm & 2047, h = gn >> 6, d = gn & 63;
          reinterpret_cast<unsigned short*>(
              Cout)[(((size_t)(b * H_ + h) * S_ + s) << 6) + d] =
              (unsigned short)bf16rz(val);
        } else if constexpr (EPI == 1) {
          int b = gm >> 11, s = gm & 2047, h = gn >> 6, d = gn & 63;
          reinterpret_cast<unsigned short*>(
              Cout)[(((size_t)(b * H_ + h) * HD_ + d) << 11) + s] =
              (unsigned short)bf16rz(val);
        } else {
          ((float*)Cout)[(size_t)gm * D_ + gn] = val;
        }
      }
    }
  }
}

// ---------------- Flash attention: intra-block split-KV, 8 waves = 2 KV groups --------
// Block owns 128 q-rows (one qt unit). Wave-group gp = w>>2 scans its KV half:
// gp0 -> tiles [0,nth), gp1 -> [nth,nt). The heavy unit's serial KV chain HALVES
// (this was the makespan: 512 units on 512 slots = zero scheduling slack).
// Each group: private 2-buffer LDS stream, R5-validated stage->compute->vmcnt(0)->
// barrier schedule; block-wide barriers stay legal because both groups run nth
// iterations with inactive-tail guards that still reach every barrier.
// Combine: LDS only (33KB scratch in dead staging buffers), one barrier, fp32 add
// in gp0's registers (exact), then the standard epilogue. No global mem, no fences
// (the R13 failure mode). Units = 1024 on 512 blocks -> heavy ranks fully resident.
__global__ __launch_bounds__(512) void attn(const __hip_bfloat16* __restrict__ Qh,
                                            const __hip_bfloat16* __restrict__ Kh,
                                            const __hip_bfloat16* __restrict__ Vt,
                                            const int* __restrict__ vlens,
                                            __hip_bfloat16* __restrict__ O,
                                            int* __restrict__ ctr) {
  const int t = threadIdx.x, lane = t & 63, w = t >> 6;  // w in 0..7
  const int gp = w >> 2, wq = w & 3;  // KV half-group, row group within group
  const int q = lane & 31;   // q-row owned by this lane
  const int hh = lane >> 5;  // half-wave

  // heavy-first batch order via stable 4-element sorting network
  int va = vlens[0], vb = vlens[1], vc = vlens[2], vd = vlens[3];
  int ia = 0, ib = 1, ic = 2, id_ = 3;
  {
    int tv, ti;
#define CSWAP(x, xi, y, yi) \
    if (y > x) { tv = x; x = y; y = tv; ti = xi; xi = yi; yi = ti; }
    CSWAP(va, ia, vb, ib) CSWAP(vc, ic, vd, id_)
    CSWAP(va, ia, vc, ic) CSWAP(vb, ib, vd, id_)
    CSWAP(vb, ib, vc, ic)
#undef CSWAP
  }
  __shared__ int s_unit;
  __shared__ __align__(16) __hip_bfloat16 smem[2][2][8192];  // [group][buf][K 4096|V 4096]

  while (true) {
    if (t == 0) s_unit = atomicAdd(ctr, 1);
    __syncthreads();  // broadcast unit; fences last unit's LDS use vs re-staging
    const int u = s_unit;
    if (u >= 1024) break;
    const int rank = u >> 8;            // 256 units per batch rank
    const int b = (rank == 0) ? ia : (rank == 1) ? ib : (rank == 2) ? ic : id_;
    const int vlen = (rank == 0) ? va : (rank == 1) ? vb : (rank == 2) ? vc : vd;
    const int r = u & 255;
    const int h = r & 15, qt = r >> 4;  // qt in 0..15: 128-row q unit
    const int bh = b * 16 + h;

    const __hip_bfloat16* Qb = Qh + (size_t)bh * S_ * HD_;
    const __hip_bfloat16* Kb = Kh + (size_t)bh * S_ * HD_;
    const __hip_bfloat16* Vb = Vt + (size_t)bh * HD_ * S_;

    const int qrow = qt * 128 + wq * 32 + q;
    bf16x8 qf[4];
#pragma unroll
    for (int kk = 0; kk < 4; ++kk)
      qf[kk] = *reinterpret_cast<const bf16x8*>(Qb + (size_t)qrow * HD_ + kk * 16 + hh * 8);

    f32x16 accT[2] = {};  // O^T partial for this KV half; col=q
    float l_half = 0.f;

    const int srow = lane >> 3;  // 0..7
    const int sg = lane & 7;     // 16B granule in 128B row
    const float maskv = (vlen == 0) ? 0.f : NEGV;
    const int kv_end = (vlen == 0) ? S_ : min(S_, (vlen + 63) & ~63);
    const int nt = kv_end >> 6;
    const int nth = (nt + 1) >> 1;       // iterations (max of the two halves)
    const int g0 = gp ? nth : 0;         // this group's first tile
    const int nloc = gp ? (nt - nth) : nth;  // this group's tile count

    // group stage: 4 waves cover the 64-row K tile + V^T tile (4 gld_lds/wave)
    auto stage = [&](int buf, int tt) {
      int kv = (g0 + tt) * 64;
#pragma unroll
      for (int c = 0; c < 2; ++c) {
        int rr = wq * 16 + c * 8 + srow;
        int gs = sg ^ (rr & 7);
        gld_lds16(Kb + (size_t)(kv + rr) * HD_ + gs * 8,
                  smem[gp][buf] + (wq * 16 + c * 8) * 64);
        gld_lds16(Vb + (size_t)rr * S_ + kv + gs * 8,
                  smem[gp][buf] + 4096 + (wq * 16 + c * 8) * 64);
      }
    };

    if (nloc > 0) stage(0, 0);
    asm volatile("s_waitcnt vmcnt(0)" ::: "memory");
    __syncthreads();
    int cur = 0;

    for (int tt = 0; tt < nth; ++tt) {
      const bool act = tt < nloc;
      if (act && tt + 1 < nloc) stage(cur ^ 1, tt + 1);  // prefetch overlaps compute
      if (act) {
        const __hip_bfloat16* Ks = smem[gp][cur];
        const __hip_bfloat16* Vs = smem[gp][cur] + 4096;

        // S^T tiles (log2-domain scores; Q carried the 0.125*log2e scale)
        f32x16 sc[2];
#pragma unroll
        for (int ct = 0; ct < 2; ++ct) {
          f32x16 a = {};
#pragma unroll
          for (int kk = 0; kk < 4; ++kk) {
            int row = ct * 32 + q;
            bf16x8 kf = *reinterpret_cast<const bf16x8*>(
                Ks + row * 64 + (((kk * 2 + hh) ^ (row & 7)) << 3));
            a = mfma32(kf, qf[kk], a);
          }
          sc[ct] = a;
        }

        // padding mask (boundary tile only; wave-uniform branch)
        int kv = (g0 + tt) * 64;
        if (kv + 64 > vlen) {
#pragma unroll
          for (int ct = 0; ct < 2; ++ct)
#pragma unroll
            for (int rr = 0; rr < 16; ++rr) {
              int j = kv + ct * 32 + (rr & 3) + 8 * (rr >> 2) + 4 * hh;
              if (j >= vlen) sc[ct][rr] = maskv;
            }
        }

        // exp (raw v_exp_f32) + bit-trick pack into 16 bf16x2 words
        uint wlo[8], whi[8];
        float rs = 0.f;
#pragma unroll
        for (int a2 = 0; a2 < 8; ++a2) {
          float p0 = exp2_hw(sc[a2 >> 2][(a2 & 3) * 4 + 0]);
          float p1 = exp2_hw(sc[a2 >> 2][(a2 & 3) * 4 + 1]);
          float p2 = exp2_hw(sc[a2 >> 2][(a2 & 3) * 4 + 2]);
          float p3 = exp2_hw(sc[a2 >> 2][(a2 & 3) * 4 + 3]);
          rs += (p0 + p1) + (p2 + p3);
          wlo[a2] = pk2bf(p0, p1);
          whi[a2] = pk2bf(p2, p3);
        }
        l_half += rs;

        // PV: B-frag = P[q][kk*16 + hh*8 + i]; half-wave exchange fills missing slots
#pragma unroll
        for (int kk = 0; kk < 4; ++kk) {
          uint glo = wlo[2 * kk], ghi = whi[2 * kk];
          uint flo = wlo[2 * kk + 1], fhi = whi[2 * kk + 1];
          uint slo = hh ? glo : flo, shi = hh ? ghi : fhi;
          uint rlo = __shfl_xor(slo, 32), rhi = __shfl_xor(shi, 32);
          union { uint u[4]; bf16x8 v; } pf;
          pf.u[0] = hh ? rlo : glo;
          pf.u[1] = hh ? rhi : ghi;
          pf.u[2] = hh ? flo : rlo;
          pf.u[3] = hh ? fhi : rhi;
#pragma unroll
          for (int ctd = 0; ctd < 2; ++ctd) {
            int vr = ctd * 32 + q;
            bf16x8 vf = *reinterpret_cast<const bf16x8*>(
                Vs + vr * 64 + (((kk * 2 + hh) ^ (vr & 7)) << 3));
            accT[ctd] = mfma32(vf, pf.v, accT[ctd]);
          }
        }
      }
      // group-uniform drain + block barrier (R5-validated schedule, per group)
      asm volatile("s_waitcnt vmcnt(0)" ::: "memory");
      __syncthreads();
      cur ^= 1;
    }

    // ---- intra-block combine: gp1's partial -> LDS -> add into gp0's registers ----
    float* comb = (float*)smem;              // 256 threads x 32 fp32 (32KB)
    float* combl = ((float*)smem) + 8192;    // + 256 fp32 (1KB); total 33KB < 64KB
    const int idx = wq * 64 + lane;
    if (gp == 1) {
#pragma unroll
      for (int ctd = 0; ctd < 2; ++ctd)
#pragma unroll
        for (int a2 = 0; a2 < 4; ++a2)
          *reinterpret_cast<float4*>(comb + idx * 32 + ctd * 16 + a2 * 4) =
              make_float4(accT[ctd][a2 * 4 + 0], accT[ctd][a2 * 4 + 1],
                          accT[ctd][a2 * 4 + 2], accT[ctd][a2 * 4 + 3]);
      combl[idx] = l_half;
    }
    __syncthreads();
    if (gp == 0) {
#pragma unroll
      for (int ctd = 0; ctd < 2; ++ctd)
#pragma unroll
        for (int a2 = 0; a2 < 4; ++a2) {
          float4 v4 = *reinterpret_cast<const float4*>(comb + idx * 32 + ctd * 16 + a2 * 4);
          accT[ctd][a2 * 4 + 0] += v4.x;
          accT[ctd][a2 * 4 + 1] += v4.y;
          accT[ctd][a2 * 4 + 2] += v4.z;
          accT[ctd][a2 * 4 + 3] += v4.w;
        }
      l_half += combl[idx];

      // epilogue (gp0 only): O^T -> O via per-wave LDS transpose, coalesced stores.
      // Ot region at bf16 offset 20480 (40KB) — clear of the 33KB combine area.
      float l_tot = l_half + __shfl_xor(l_half, 32);
      float inv = 1.f / l_tot;
      __hip_bfloat16* Ot = ((__hip_bfloat16*)smem) + 20480 + wq * 2048;  // [32 q][64 d]
#pragma unroll
      for (int ctd = 0; ctd < 2; ++ctd)
#pragma unroll
        for (int a2 = 0; a2 < 4; ++a2) {
          uint2 o;
          o.x = pk2bf(accT[ctd][a2 * 4 + 0] * inv, accT[ctd][a2 * 4 + 1] * inv);
          o.y = pk2bf(accT[ctd][a2 * 4 + 2] * inv, accT[ctd][a2 * 4 + 3] * inv);
          int gs8 = (ctd * 8 + a2 * 2 + hh) ^ ((q & 7) << 1);
          *reinterpret_cast<uint2*>(Ot + q * 64 + gs8 * 4) = o;
        }
#pragma unroll
      for (int rr = 0; rr < 4; ++rr) {
        int row = rr * 8 + (lane >> 3);  // q-row within wave tile
        int c16 = lane & 7;              // 16B chunk of d
        float4 v4 = *reinterpret_cast<const float4*>(
            Ot + row * 64 + (((c16 * 2) ^ ((row & 7) << 1)) << 2));
        int s = qt * 128 + wq * 32 + row;
        *reinterpret_cast<float4*>(O + ((size_t)b * S_ + s) * D_ + h * HD_ + c16 * 8) = v4;
      }
    }
    // top-of-loop barrier protects smem (combine + Ot areas) before re-staging
  }
}

extern "C" void kernel_launch(void* const* d_in, const int* in_sizes, int n_in,
                              void* d_out, int out_size, void* d_ws, size_t ws_size,
                              hipStream_t stream) {
  const float* Xq = (const float*)d_in[0];
  const float* Xk = (const float*)d_in[1];
  const float* Xv = (const float*)d_in[2];
  const int* vl = (const int*)d_in[3];
  const float* Wq = (const float*)d_in[4];
  const float* Wk = (const float*)d_in[5];
  const float* Wv = (const float*)d_in[6];
  const float* Wo = (const float*)d_in[7];
  float* out = (float*)d_out;

  char* ws = (char*)d_ws;
  const size_t XB = (size_t)M_ * D_ * 2;   // 16 MB bf16 [8192][1024]
  const size_t WB = (size_t)D_ * D_ * 2;   // 2 MB bf16 [1024][1024]
  __hip_bfloat16* xq = (__hip_bfloat16*)(ws);                    // Xq bf16, later Obuf
  __hip_bfloat16* xk = (__hip_bfloat16*)(ws + XB);               // Xk bf16, later ctr
  __hip_bfloat16* xv = (__hip_bfloat16*)(ws + 2 * XB);           // Xv bf16
  __hip_bfloat16* wtq = (__hip_bfloat16*)(ws + 3 * XB);          // wtq..wto contiguous
  __hip_bfloat16* wto = (__hip_bfloat16*)(ws + 3 * XB + 3 * WB);
  __hip_bfloat16* Qh = (__hip_bfloat16*)(ws + 3 * XB + 4 * WB);      // [B][H][S][HD]
  __hip_bfloat16* Kh = (__hip_bfloat16*)(ws + 4 * XB + 4 * WB);      // [B][H][S][HD]
  __hip_bfloat16* Vh = (__hip_bfloat16*)(ws + 5 * XB + 4 * WB);      // [B][H][HD][S]
  __hip_bfloat16* Obuf = xq;      // alias: xq dead after the Q projection GEMM
  int* ctr = (int*)xk;            // alias: xk dead after the K projection GEMM

  convert_wt4<<<dim3(32, 32, 4), dim3(32, 8), 0, stream>>>(Wq, Wk, Wv, Wo, wtq);

  const int n4 = M_ * D_ / 4;
  convert_x3<<<dim3(n4 / 256, 3), 256, 0, stream>>>(Xq, Xk, Xv, xq, xk, xv, n4, vl);

  // fused Q/K/V projections: one 1536-block dispatch
  gemm_qkv<<<dim3(M_ / 128, D_ / 128, 3), 256, 0, stream>>>(xq, xk, xv, wtq,
                                                            Qh, Kh, Vh, vl);

  hipMemsetAsync(ctr, 0, sizeof(int), stream);  // reset work-stealing counter
  attn<<<dim3(512), 512, 0, stream>>>(Qh, Kh, Vh, vl, Obuf, ctr);
  gemm_bt<2><<<dim3(M_ / 128, D_ / 128), 256, 0, stream>>>(Obuf, wto, out, nullptr, 1.0f);
}

// Round 18
// 201.656 us; speedup vs baseline: 1.0430x; 1.0430x over previous
//
#include <hip/hip_runtime.h>
#include <hip/hip_bf16.h>

// Problem constants
#define B_ 4
#define S_ 2048
#define D_ 1024
#define H_ 16
#define HD_ 64
#define M_ 8192           // B*S
#define NEGV -1000000.0f
#define CEXP 0.18033688011112042f   // (1/sqrt(HD)) * log2(e) — folded into Q projection

typedef __attribute__((ext_vector_type(8))) __bf16 bf16x8;
typedef __attribute__((ext_vector_type(4))) float f32x4;
typedef __attribute__((ext_vector_type(16))) float f32x16;

__device__ __forceinline__ f32x4 mfma16(bf16x8 a, bf16x8 b, f32x4 c) {
  return __builtin_amdgcn_mfma_f32_16x16x32_bf16(a, b, c, 0, 0, 0);
}
__device__ __forceinline__ f32x16 mfma32(bf16x8 a, bf16x8 b, f32x16 c) {
  return __builtin_amdgcn_mfma_f32_32x32x16_bf16(a, b, c, 0, 0, 0);
}

// raw v_exp_f32 (exp2f without -ffast-math is a guarded libm sequence)
#if __has_builtin(__builtin_amdgcn_exp2f)
__device__ __forceinline__ float exp2_hw(float x) { return __builtin_amdgcn_exp2f(x); }
#else
__device__ __forceinline__ float exp2_hw(float x) {
  float r;
  asm volatile("v_exp_f32 %0, %1" : "=v"(r) : "v"(x));
  return r;
}
#endif

// Branchless RNE fp32->bf16 (exact for all finite values; no NaNs in this pipeline).
__device__ __forceinline__ unsigned bf16rz(float x) {
  unsigned u = __float_as_uint(x);
  return (u + 0x7FFFu + ((u >> 16) & 1u)) >> 16;
}
// pack two floats -> bf16x2 word (lo = a, hi = b)
__device__ __forceinline__ unsigned pk2bf(float a, float b) {
  unsigned ua = __float_as_uint(a), ub = __float_as_uint(b);
  ua = ua + 0x7FFFu + ((ua >> 16) & 1u);
  ub = ub + 0x7FFFu + ((ub >> 16) & 1u);
  return (ua >> 16) | (ub & 0xFFFF0000u);
}

// async global->LDS, 16B per lane. LDS dest is wave-uniform base (HW adds lane*16).
__device__ __forceinline__ void gld_lds16(const __hip_bfloat16* g, __hip_bfloat16* l) {
  __builtin_amdgcn_global_load_lds(
      (const __attribute__((address_space(1))) void*)g,
      (__attribute__((address_space(3))) void*)l, 16, 0, 0);
}

// ---------------- fp32 -> bf16 convert, all three X tensors in one launch -------------
__global__ __launch_bounds__(256) void convert_x3(const float* __restrict__ Xq,
                                                  const float* __restrict__ Xk,
                                                  const float* __restrict__ Xv,
                                                  __hip_bfloat16* __restrict__ Yq,
                                                  __hip_bfloat16* __restrict__ Yk,
                                                  __hip_bfloat16* __restrict__ Yv,
                                                  int n4, const int* __restrict__ vl) {
  const int z = blockIdx.y;
  const float* X = (z == 0) ? Xq : (z == 1) ? Xk : Xv;
  __hip_bfloat16* Y = (z == 0) ? Yq : (z == 1) ? Yk : Yv;
  int i = blockIdx.x * blockDim.x + threadIdx.x;
  if (i >= n4) return;
  if (z) {
    int gm = i >> 8;  // 256 float4 per 1024-wide row
    int vlen = vl[gm >> 11];
    if (vlen > 0 && (gm & 2047) >= ((vlen + 63) & ~63)) return;
  }
  float4 v = reinterpret_cast<const float4*>(X)[i];
  uint2 o;
  o.x = pk2bf(v.x, v.y);
  o.y = pk2bf(v.z, v.w);
  reinterpret_cast<uint2*>(Y)[i] = o;
}

// ---------------- 4x W[1024][1024] fp32 -> W^T bf16 (fused via blockIdx.z) -----------
__global__ __launch_bounds__(256) void convert_wt4(const float* __restrict__ W0,
                                                   const float* __restrict__ W1,
                                                   const float* __restrict__ W2,
                                                   const float* __restrict__ W3,
                                                   __hip_bfloat16* __restrict__ WtBase) {
  const int z = blockIdx.z;
  const float* W = (z == 0) ? W0 : (z == 1) ? W1 : (z == 2) ? W2 : W3;
  __hip_bfloat16* Wt = WtBase + (size_t)z * D_ * D_;
  __shared__ float tile[32][33];
  int c0 = blockIdx.x * 32, r0 = blockIdx.y * 32;
  int tx = threadIdx.x, ty = threadIdx.y;
#pragma unroll
  for (int rr = ty; rr < 32; rr += 8)
    tile[rr][tx] = W[(size_t)(r0 + rr) * D_ + c0 + tx];
  __syncthreads();
#pragma unroll
  for (int rr = ty; rr < 32; rr += 8)
    reinterpret_cast<unsigned short*>(Wt)[(size_t)(c0 + rr) * D_ + r0 + tx] =
        (unsigned short)bf16rz(tile[tx][rr]);
}

// ---------------- GEMM: C[M,N] = A[M,K] * Bt[N,K]^T  (bf16 in, templated epilogue) ----
// BK=64, XOR-swizzled LDS (T2), double-buffered 2-phase schedule (R9-R15-validated).
// LDS invariant: LDS[row][g] = global[row][g ^ (row&7)] (16B granules, involution).
// SEPARATE launches per projection (R16's z-fused dispatch broke the per-XCD
// {A-panel + W} L2 working set and regressed).
template <int EPI>
__global__ __launch_bounds__(256) void gemm_bt(const __hip_bfloat16* __restrict__ A,
                                               const __hip_bfloat16* __restrict__ Bt,
                                               void* __restrict__ Cout,
                                               const int* __restrict__ vskip,
                                               float cscale) {
  int id = blockIdx.y * gridDim.x + blockIdx.x;
  int cpx = (gridDim.x * gridDim.y) >> 3;
  int nid = (id & 7) * cpx + (id >> 3);
  const int m0 = (nid >> 3) * 128, n0 = (nid & 7) * 128;
  if (vskip) {
    int vlen = vskip[m0 >> 11];
    if (vlen > 0 && (m0 & 2047) >= ((vlen + 63) & ~63)) return;
  }
  const int t = threadIdx.x, lane = t & 63, wid = t >> 6;
  const int lc = lane & 15, g = lane >> 4;
  const int srow8 = lane >> 3, sg8 = lane & 7;
  __shared__ __align__(16) __hip_bfloat16 smem[2][2][128 * 64];  // [buf][A/B][tile] 64KB
  f32x4 acc[4][4] = {};
  const int wm = (wid & 1) * 64, wn = (wid >> 1) * 64;

  auto stage = [&](int buf, int k0) {
#pragma unroll
    for (int c = 0; c < 4; ++c) {
      int ci = c * 4 + wid;              // 1KB chunk index (8 rows)
      int row = ci * 8 + srow8;          // this lane's source row
      int sg = sg8 ^ (row & 7);          // inverse-swizzled source granule
      gld_lds16(A + (size_t)(m0 + row) * D_ + k0 + sg * 8, &smem[buf][0][ci * 512]);
      gld_lds16(Bt + (size_t)(n0 + row) * D_ + k0 + sg * 8, &smem[buf][1][ci * 512]);
    }
  };

  stage(0, 0);
  asm volatile("s_waitcnt vmcnt(0)" ::: "memory");
  __syncthreads();
  int cur = 0;

  for (int kt = 0; kt < D_ / 64; ++kt) {
    if (kt + 1 < D_ / 64) stage(cur ^ 1, (kt + 1) * 64);  // prefetch overlaps compute
    const __hip_bfloat16* As = smem[cur][0];
    const __hip_bfloat16* Bs = smem[cur][1];
#pragma unroll
    for (int kh = 0; kh < 2; ++kh) {  // two K=32 halves of the K=64 tile
      bf16x8 af[4], bf[4];
#pragma unroll
      for (int mi = 0; mi < 4; ++mi) {
        int r = wm + mi * 16 + lc;
        af[mi] = *reinterpret_cast<const bf16x8*>(
            As + r * 64 + (((kh * 4 + g) ^ (r & 7)) << 3));
        int rn = wn + mi * 16 + lc;
        bf[mi] = *reinterpret_cast<const bf16x8*>(
            Bs + rn * 64 + (((kh * 4 + g) ^ (rn & 7)) << 3));
      }
#pragma unroll
      for (int mi = 0; mi < 4; ++mi)
#pragma unroll
        for (int ni = 0; ni < 4; ++ni)
          acc[mi][ni] = mfma16(af[mi], bf[ni], acc[mi][ni]);
    }
    asm volatile("s_waitcnt vmcnt(0)" ::: "memory");
    __syncthreads();
    cur ^= 1;
  }

#pragma unroll
  for (int mi = 0; mi < 4; ++mi) {
#pragma unroll
    for (int ni = 0; ni < 4; ++ni) {
#pragma unroll
      for (int i = 0; i < 4; ++i) {
        int gm = m0 + wm + mi * 16 + g * 4 + i;
        int gn = n0 + wn + ni * 16 + lc;
        float val = acc[mi][ni][i] * cscale;
        if constexpr (EPI == 0) {
          int b = gm >> 11, s = gm & 2047, h = gn >> 6, d = gn & 63;
          reinterpret_cast<unsigned short*>(
              Cout)[(((size_t)(b * H_ + h) * S_ + s) << 6) + d] =
              (unsigned short)bf16rz(val);
        } else if constexpr (EPI == 1) {
          int b = gm >> 11, s = gm & 2047, h = gn >> 6, d = gn & 63;
          reinterpret_cast<unsigned short*>(
              Cout)[(((size_t)(b * H_ + h) * HD_ + d) << 11) + s] =
              (unsigned short)bf16rz(val);
        } else {
          ((float*)Cout)[(size_t)gm * D_ + gn] = val;
        }
      }
    }
  }
}

// ---------------- Flash attention: 8-wave blocks, 2 q-units per K/V stream ------------
// R15 verbatim (best measured config: 90.3 us). Each block owns 256 q-rows (two
// adjacent 128-row qt units of one (b,h)) across 8 waves sharing one staged K/V
// stream; 3-buffer ring with counted vmcnt(2) (retire own stage(tt), keep
// stage(tt+1) in flight), vmcnt(0) on the last iteration. No setprio (R16: -2%,
// lockstep waves give the scheduler nothing to arbitrate — m190-class null).
__global__ __launch_bounds__(512) void attn(const __hip_bfloat16* __restrict__ Qh,
                                            const __hip_bfloat16* __restrict__ Kh,
                                            const __hip_bfloat16* __restrict__ Vt,
                                            const int* __restrict__ vlens,
                                            __hip_bfloat16* __restrict__ O,
                                            int* __restrict__ ctr) {
  const int t = threadIdx.x, lane = t & 63, w = t >> 6;  // w in 0..7
  const int wq = w & 3, up = w >> 2;  // sub-wave row group, unit half
  const int q = lane & 31;   // q-row owned by this lane
  const int hh = lane >> 5;  // half-wave

  // heavy-first batch order via stable 4-element sorting network
  int va = vlens[0], vb = vlens[1], vc = vlens[2], vd = vlens[3];
  int ia = 0, ib = 1, ic = 2, id_ = 3;
  {
    int tv, ti;
#define CSWAP(x, xi, y, yi) \
    if (y > x) { tv = x; x = y; y = tv; ti = xi; xi = yi; yi = ti; }
    CSWAP(va, ia, vb, ib) CSWAP(vc, ic, vd, id_)
    CSWAP(va, ia, vc, ic) CSWAP(vb, ib, vd, id_)
    CSWAP(vb, ib, vc, ic)
#undef CSWAP
  }
  __shared__ int s_unit;
  __shared__ __align__(16) __hip_bfloat16 smem[3][8192];  // ring [buf][ Ks 64x64 | Vs ]

  while (true) {
    if (t == 0) s_unit = atomicAdd(ctr, 1);
    __syncthreads();  // broadcast unit; also fences last unit's LDS use vs re-staging
    const int u = s_unit;
    if (u >= 512) break;
    const int rank = u >> 7;            // 128 units per batch rank
    const int b = (rank == 0) ? ia : (rank == 1) ? ib : (rank == 2) ? ic : id_;
    const int vlen = (rank == 0) ? va : (rank == 1) ? vb : (rank == 2) ? vc : vd;
    const int r = u & 127;
    const int h = r & 15, qtp = r >> 4;  // qtp in 0..7: 256-row q-pair
    const int bh = b * 16 + h;

    const __hip_bfloat16* Qb = Qh + (size_t)bh * S_ * HD_;
    const __hip_bfloat16* Kb = Kh + (size_t)bh * S_ * HD_;
    const __hip_bfloat16* Vb = Vt + (size_t)bh * HD_ * S_;

    const int qrow = qtp * 256 + up * 128 + wq * 32 + q;
    bf16x8 qf[4];
#pragma unroll
    for (int kk = 0; kk < 4; ++kk)
      qf[kk] = *reinterpret_cast<const bf16x8*>(Qb + (size_t)qrow * HD_ + kk * 16 + hh * 8);

    f32x16 accT[2] = {};  // O^T: accT[ctd] reg r -> d = ctd*32+(r&3)+8*(r>>2)+4*hh, col=q
    float l_half = 0.f;

    const int srow = lane >> 3;  // 0..7
    const int sg = lane & 7;     // 16B granule in 128B row
    const float maskv = (vlen == 0) ? 0.f : NEGV;
    const int kv_end = (vlen == 0) ? S_ : min(S_, (vlen + 63) & ~63);
    const int nt = kv_end >> 6;

    // stage: 8 waves cover the 64-row K tile and 64-row V^T tile; wave w stages
    // rows [w*8, w*8+8) of each -> 2 gld_lds per wave per stage.
    auto stage = [&](int buf, int tile) {
      int kv = tile * 64;
      int rr = w * 8 + srow;
      int gs = sg ^ (rr & 7);
      gld_lds16(Kb + (size_t)(kv + rr) * HD_ + gs * 8, smem[buf] + (w * 8) * 64);
      gld_lds16(Vb + (size_t)rr * S_ + kv + gs * 8, smem[buf] + 4096 + (w * 8) * 64);
    };

    // prologue: fill pipeline to depth 2 (no drain — iter 0's vmcnt handles it)
    stage(0, 0);
    if (nt > 1) stage(1, 1);
    int bc = 0;                         // buffer of current tile (tt%3)
    int bs = (nt > 2) ? 2 : 0;          // buffer for stage(tt+2)

    for (int tt = 0; tt < nt; ++tt) {
      // retire own stage(tt) (2 loads); allow stage(tt+1)'s 2 to stay in flight
      if (tt + 1 < nt) {
        asm volatile("s_waitcnt vmcnt(2)" ::: "memory");
      } else {
        asm volatile("s_waitcnt vmcnt(0)" ::: "memory");
      }
      __syncthreads();  // all waves' stage(tt) LDS-writes visible; compute(tt-1) done
      if (tt + 2 < nt) stage(bs, tt + 2);

      const __hip_bfloat16* Ks = smem[bc];
      const __hip_bfloat16* Vs = smem[bc] + 4096;

      // S^T tiles (log2-domain scores; Q carried the 0.125*log2e scale)
      f32x16 sc[2];
#pragma unroll
      for (int ct = 0; ct < 2; ++ct) {
        f32x16 a = {};
#pragma unroll
        for (int kk = 0; kk < 4; ++kk) {
          int row = ct * 32 + q;
          bf16x8 kf = *reinterpret_cast<const bf16x8*>(
              Ks + row * 64 + (((kk * 2 + hh) ^ (row & 7)) << 3));
          a = mfma32(kf, qf[kk], a);
        }
        sc[ct] = a;
      }

      // padding mask (boundary tile only; wave-uniform branch)
      int kv = tt * 64;
      if (kv + 64 > vlen) {
#pragma unroll
        for (int ct = 0; ct < 2; ++ct)
#pragma unroll
          for (int rr = 0; rr < 16; ++rr) {
            int j = kv + ct * 32 + (rr & 3) + 8 * (rr >> 2) + 4 * hh;
            if (j >= vlen) sc[ct][rr] = maskv;
          }
      }

      // exp (raw v_exp_f32) + bit-trick pack into 16 bf16x2 words
      uint wlo[8], whi[8];
      float rs = 0.f;
#pragma unroll
      for (int a2 = 0; a2 < 8; ++a2) {
        float p0 = exp2_hw(sc[a2 >> 2][(a2 & 3) * 4 + 0]);
        float p1 = exp2_hw(sc[a2 >> 2][(a2 & 3) * 4 + 1]);
        float p2 = exp2_hw(sc[a2 >> 2][(a2 & 3) * 4 + 2]);
        float p3 = exp2_hw(sc[a2 >> 2][(a2 & 3) * 4 + 3]);
        rs += (p0 + p1) + (p2 + p3);
        wlo[a2] = pk2bf(p0, p1);
        whi[a2] = pk2bf(p2, p3);
      }
      l_half += rs;

      // PV: B-frag = P[q][kk*16 + hh*8 + i]; half-wave exchange fills the missing slots
#pragma unroll
      for (int kk = 0; kk < 4; ++kk) {
        uint glo = wlo[2 * kk], ghi = whi[2 * kk];
        uint flo = wlo[2 * kk + 1], fhi = whi[2 * kk + 1];
        uint slo = hh ? glo : flo, shi = hh ? ghi : fhi;
        uint rlo = __shfl_xor(slo, 32), rhi = __shfl_xor(shi, 32);
        union { uint u[4]; bf16x8 v; } pf;
        pf.u[0] = hh ? rlo : glo;
        pf.u[1] = hh ? rhi : ghi;
        pf.u[2] = hh ? flo : rlo;
        pf.u[3] = hh ? fhi : rhi;
#pragma unroll
        for (int ctd = 0; ctd < 2; ++ctd) {
          int vr = ctd * 32 + q;
          bf16x8 vf = *reinterpret_cast<const bf16x8*>(
              Vs + vr * 64 + (((kk * 2 + hh) ^ (vr & 7)) << 3));
          accT[ctd] = mfma32(vf, pf.v, accT[ctd]);
        }
      }
      bc = (bc == 2) ? 0 : bc + 1;
      bs = (bs == 2) ? 0 : bs + 1;
    }
    __syncthreads();  // all waves out of the ring before epilogue reuses smem

    // epilogue: O^T -> O via per-wave LDS transpose (same-wave ordering, no barrier).
    float l_tot = l_half + __shfl_xor(l_half, 32);
    float inv = 1.f / l_tot;
    __hip_bfloat16* Ot = smem[0] + w * 2048;  // [32 q][64 d], 8B-granule swizzle
#pragma unroll
    for (int ctd = 0; ctd < 2; ++ctd)
#pragma unroll
      for (int a2 = 0; a2 < 4; ++a2) {
        uint2 o;
        o.x = pk2bf(accT[ctd][a2 * 4 + 0] * inv, accT[ctd][a2 * 4 + 1] * inv);
        o.y = pk2bf(accT[ctd][a2 * 4 + 2] * inv, accT[ctd][a2 * 4 + 3] * inv);
        int gs8 = (ctd * 8 + a2 * 2 + hh) ^ ((q & 7) << 1);
        *reinterpret_cast<uint2*>(Ot + q * 64 + gs8 * 4) = o;
      }
#pragma unroll
    for (int rr = 0; rr < 4; ++rr) {
      int row = rr * 8 + (lane >> 3);  // q-row within wave tile
      int c16 = lane & 7;              // 16B chunk of d
      float4 v4 = *reinterpret_cast<const float4*>(
          Ot + row * 64 + (((c16 * 2) ^ ((row & 7) << 1)) << 2));
      int s = qtp * 256 + up * 128 + wq * 32 + row;
      *reinterpret_cast<float4*>(O + ((size_t)b * S_ + s) * D_ + h * HD_ + c16 * 8) = v4;
    }
  }
}

extern "C" void kernel_launch(void* const* d_in, const int* in_sizes, int n_in,
                              void* d_out, int out_size, void* d_ws, size_t ws_size,
                              hipStream_t stream) {
  const float* Xq = (const float*)d_in[0];
  const float* Xk = (const float*)d_in[1];
  const float* Xv = (const float*)d_in[2];
  const int* vl = (const int*)d_in[3];
  const float* Wq = (const float*)d_in[4];
  const float* Wk = (const float*)d_in[5];
  const float* Wv = (const float*)d_in[6];
  const float* Wo = (const float*)d_in[7];
  float* out = (float*)d_out;

  char* ws = (char*)d_ws;
  const size_t XB = (size_t)M_ * D_ * 2;   // 16 MB bf16 [8192][1024]
  const size_t WB = (size_t)D_ * D_ * 2;   // 2 MB bf16 [1024][1024]
  __hip_bfloat16* xq = (__hip_bfloat16*)(ws);                    // Xq bf16, later Obuf
  __hip_bfloat16* xk = (__hip_bfloat16*)(ws + XB);               // Xk bf16, later ctr
  __hip_bfloat16* xv = (__hip_bfloat16*)(ws + 2 * XB);           // Xv bf16
  __hip_bfloat16* wtq = (__hip_bfloat16*)(ws + 3 * XB);          // wtq..wto contiguous
  __hip_bfloat16* wtk = (__hip_bfloat16*)(ws + 3 * XB + WB);
  __hip_bfloat16* wtv = (__hip_bfloat16*)(ws + 3 * XB + 2 * WB);
  __hip_bfloat16* wto = (__hip_bfloat16*)(ws + 3 * XB + 3 * WB);
  __hip_bfloat16* Qh = (__hip_bfloat16*)(ws + 3 * XB + 4 * WB);      // [B][H][S][HD]
  __hip_bfloat16* Kh = (__hip_bfloat16*)(ws + 4 * XB + 4 * WB);      // [B][H][S][HD]
  __hip_bfloat16* Vh = (__hip_bfloat16*)(ws + 5 * XB + 4 * WB);      // [B][H][HD][S]
  __hip_bfloat16* Obuf = xq;      // alias: xq dead after the Q projection GEMM
  int* ctr = (int*)xk;            // alias: xk dead after the K projection GEMM

  convert_wt4<<<dim3(32, 32, 4), dim3(32, 8), 0, stream>>>(Wq, Wk, Wv, Wo, wtq);

  const int n4 = M_ * D_ / 4;
  convert_x3<<<dim3(n4 / 256, 3), 256, 0, stream>>>(Xq, Xk, Xv, xq, xk, xv, n4, vl);

  dim3 gg(M_ / 128, D_ / 128);
  gemm_bt<0><<<gg, 256, 0, stream>>>(xq, wtq, Qh, nullptr, CEXP);  // Q carries softmax scale
  gemm_bt<0><<<gg, 256, 0, stream>>>(xk, wtk, Kh, vl, 1.0f);
  gemm_bt<1><<<gg, 256, 0, stream>>>(xv, wtv, Vh, vl, 1.0f);

  hipMemsetAsync(ctr, 0, sizeof(int), stream);  // reset work-stealing counter
  attn<<<dim3(512), 512, 0, stream>>>(Qh, Kh, Vh, vl, Obuf, ctr);
  gemm_bt<2><<<gg, 256, 0, stream>>>(Obuf, wto, out, nullptr, 1.0f);
}

// Round 19
// 194.695 us; speedup vs baseline: 1.0803x; 1.0358x over previous
//
#include <hip/hip_runtime.h>
#include <hip/hip_bf16.h>

// Problem constants
#define B_ 4
#define S_ 2048
#define D_ 1024
#define H_ 16
#define HD_ 64
#define M_ 8192           // B*S
#define NEGV -1000000.0f
#define CEXP 0.18033688011112042f   // (1/sqrt(HD)) * log2(e) — folded into Q projection

typedef __attribute__((ext_vector_type(8))) __bf16 bf16x8;
typedef __attribute__((ext_vector_type(4))) float f32x4;
typedef __attribute__((ext_vector_type(16))) float f32x16;

__device__ __forceinline__ f32x4 mfma16(bf16x8 a, bf16x8 b, f32x4 c) {
  return __builtin_amdgcn_mfma_f32_16x16x32_bf16(a, b, c, 0, 0, 0);
}
__device__ __forceinline__ f32x16 mfma32(bf16x8 a, bf16x8 b, f32x16 c) {
  return __builtin_amdgcn_mfma_f32_32x32x16_bf16(a, b, c, 0, 0, 0);
}

// raw v_exp_f32 (exp2f without -ffast-math is a guarded libm sequence)
#if __has_builtin(__builtin_amdgcn_exp2f)
__device__ __forceinline__ float exp2_hw(float x) { return __builtin_amdgcn_exp2f(x); }
#else
__device__ __forceinline__ float exp2_hw(float x) {
  float r;
  asm volatile("v_exp_f32 %0, %1" : "=v"(r) : "v"(x));
  return r;
}
#endif

// Branchless RNE fp32->bf16 (exact for all finite values; no NaNs in this pipeline).
__device__ __forceinline__ unsigned bf16rz(float x) {
  unsigned u = __float_as_uint(x);
  return (u + 0x7FFFu + ((u >> 16) & 1u)) >> 16;
}
// pack two floats -> bf16x2 word (lo = a, hi = b)
__device__ __forceinline__ unsigned pk2bf(float a, float b) {
  unsigned ua = __float_as_uint(a), ub = __float_as_uint(b);
  ua = ua + 0x7FFFu + ((ua >> 16) & 1u);
  ub = ub + 0x7FFFu + ((ub >> 16) & 1u);
  return (ua >> 16) | (ub & 0xFFFF0000u);
}

// async global->LDS, 16B per lane. LDS dest is wave-uniform base (HW adds lane*16).
__device__ __forceinline__ void gld_lds16(const __hip_bfloat16* g, __hip_bfloat16* l) {
  __builtin_amdgcn_global_load_lds(
      (const __attribute__((address_space(1))) void*)g,
      (__attribute__((address_space(3))) void*)l, 16, 0, 0);
}

// ---------------- fp32 -> bf16 convert, all three X tensors in one launch -------------
__global__ __launch_bounds__(256) void convert_x3(const float* __restrict__ Xq,
                                                  const float* __restrict__ Xk,
                                                  const float* __restrict__ Xv,
                                                  __hip_bfloat16* __restrict__ Yq,
                                                  __hip_bfloat16* __restrict__ Yk,
                                                  __hip_bfloat16* __restrict__ Yv,
                                                  int n4, const int* __restrict__ vl) {
  const int z = blockIdx.y;
  const float* X = (z == 0) ? Xq : (z == 1) ? Xk : Xv;
  __hip_bfloat16* Y = (z == 0) ? Yq : (z == 1) ? Yk : Yv;
  int i = blockIdx.x * blockDim.x + threadIdx.x;
  if (i >= n4) return;
  if (z) {
    int gm = i >> 8;  // 256 float4 per 1024-wide row
    int vlen = vl[gm >> 11];
    if (vlen > 0 && (gm & 2047) >= ((vlen + 63) & ~63)) return;
  }
  float4 v = reinterpret_cast<const float4*>(X)[i];
  uint2 o;
  o.x = pk2bf(v.x, v.y);
  o.y = pk2bf(v.z, v.w);
  reinterpret_cast<uint2*>(Y)[i] = o;
}

// ---------------- 4x W[1024][1024] fp32 -> W^T bf16 (fused via blockIdx.z) -----------
__global__ __launch_bounds__(256) void convert_wt4(const float* __restrict__ W0,
                                                   const float* __restrict__ W1,
                                                   const float* __restrict__ W2,
                                                   const float* __restrict__ W3,
                                                   __hip_bfloat16* __restrict__ WtBase) {
  const int z = blockIdx.z;
  const float* W = (z == 0) ? W0 : (z == 1) ? W1 : (z == 2) ? W2 : W3;
  __hip_bfloat16* Wt = WtBase + (size_t)z * D_ * D_;
  __shared__ float tile[32][33];
  int c0 = blockIdx.x * 32, r0 = blockIdx.y * 32;
  int tx = threadIdx.x, ty = threadIdx.y;
#pragma unroll
  for (int rr = ty; rr < 32; rr += 8)
    tile[rr][tx] = W[(size_t)(r0 + rr) * D_ + c0 + tx];
  __syncthreads();
#pragma unroll
  for (int rr = ty; rr < 32; rr += 8)
    reinterpret_cast<unsigned short*>(Wt)[(size_t)(c0 + rr) * D_ + r0 + tx] =
        (unsigned short)bf16rz(tile[tx][rr]);
}

// ---------------- GEMM: C[M,N] = A[M,K] * Bt[N,K]^T  (bf16 in, templated epilogue) ----
// BK=64, XOR-swizzled LDS (T2), double-buffered 2-phase schedule (R9-R18-validated).
// LDS invariant: LDS[row][g] = global[row][g ^ (row&7)] (16B granules, involution).
// SEPARATE launches per projection (R16's z-fused dispatch broke the per-XCD
// {A-panel + W} L2 working set and regressed).
template <int EPI>
__global__ __launch_bounds__(256) void gemm_bt(const __hip_bfloat16* __restrict__ A,
                                               const __hip_bfloat16* __restrict__ Bt,
                                               void* __restrict__ Cout,
                                               const int* __restrict__ vskip,
                                               float cscale) {
  int id = blockIdx.y * gridDim.x + blockIdx.x;
  int cpx = (gridDim.x * gridDim.y) >> 3;
  int nid = (id & 7) * cpx + (id >> 3);
  const int m0 = (nid >> 3) * 128, n0 = (nid & 7) * 128;
  if (vskip) {
    int vlen = vskip[m0 >> 11];
    if (vlen > 0 && (m0 & 2047) >= ((vlen + 63) & ~63)) return;
  }
  const int t = threadIdx.x, lane = t & 63, wid = t >> 6;
  const int lc = lane & 15, g = lane >> 4;
  const int srow8 = lane >> 3, sg8 = lane & 7;
  __shared__ __align__(16) __hip_bfloat16 smem[2][2][128 * 64];  // [buf][A/B][tile] 64KB
  f32x4 acc[4][4] = {};
  const int wm = (wid & 1) * 64, wn = (wid >> 1) * 64;

  auto stage = [&](int buf, int k0) {
#pragma unroll
    for (int c = 0; c < 4; ++c) {
      int ci = c * 4 + wid;              // 1KB chunk index (8 rows)
      int row = ci * 8 + srow8;          // this lane's source row
      int sg = sg8 ^ (row & 7);          // inverse-swizzled source granule
      gld_lds16(A + (size_t)(m0 + row) * D_ + k0 + sg * 8, &smem[buf][0][ci * 512]);
      gld_lds16(Bt + (size_t)(n0 + row) * D_ + k0 + sg * 8, &smem[buf][1][ci * 512]);
    }
  };

  stage(0, 0);
  asm volatile("s_waitcnt vmcnt(0)" ::: "memory");
  __syncthreads();
  int cur = 0;

  for (int kt = 0; kt < D_ / 64; ++kt) {
    if (kt + 1 < D_ / 64) stage(cur ^ 1, (kt + 1) * 64);  // prefetch overlaps compute
    const __hip_bfloat16* As = smem[cur][0];
    const __hip_bfloat16* Bs = smem[cur][1];
#pragma unroll
    for (int kh = 0; kh < 2; ++kh) {  // two K=32 halves of the K=64 tile
      bf16x8 af[4], bf[4];
#pragma unroll
      for (int mi = 0; mi < 4; ++mi) {
        int r = wm + mi * 16 + lc;
        af[mi] = *reinterpret_cast<const bf16x8*>(
            As + r * 64 + (((kh * 4 + g) ^ (r & 7)) << 3));
        int rn = wn + mi * 16 + lc;
        bf[mi] = *reinterpret_cast<const bf16x8*>(
            Bs + rn * 64 + (((kh * 4 + g) ^ (rn & 7)) << 3));
      }
#pragma unroll
      for (int mi = 0; mi < 4; ++mi)
#pragma unroll
        for (int ni = 0; ni < 4; ++ni)
          acc[mi][ni] = mfma16(af[mi], bf[ni], acc[mi][ni]);
    }
    asm volatile("s_waitcnt vmcnt(0)" ::: "memory");
    __syncthreads();
    cur ^= 1;
  }

#pragma unroll
  for (int mi = 0; mi < 4; ++mi) {
#pragma unroll
    for (int ni = 0; ni < 4; ++ni) {
#pragma unroll
      for (int i = 0; i < 4; ++i) {
        int gm = m0 + wm + mi * 16 + g * 4 + i;
        int gn = n0 + wn + ni * 16 + lc;
        float val = acc[mi][ni][i] * cscale;
        if constexpr (EPI == 0) {
          int b = gm >> 11, s = gm & 2047, h = gn >> 6, d = gn & 63;
          reinterpret_cast<unsigned short*>(
              Cout)[(((size_t)(b * H_ + h) * S_ + s) << 6) + d] =
              (unsigned short)bf16rz(val);
        } else if constexpr (EPI == 1) {
          int b = gm >> 11, s = gm & 2047, h = gn >> 6, d = gn & 63;
          reinterpret_cast<unsigned short*>(
              Cout)[(((size_t)(b * H_ + h) * HD_ + d) << 11) + s] =
              (unsigned short)bf16rz(val);
        } else {
          ((float*)Cout)[(size_t)gm * D_ + gn] = val;
        }
      }
    }
  }
}

// ---------------- Flash attention: 8-wave blocks, 2 KV tiles per barrier step ---------
// R15/R18 per-tile body verbatim. ONE parameter change: KV tiles are processed in
// PAIRS — two 32KB pair-buffers (64KB LDS, still 2 blocks/CU), schedule is the
// R5/R9/R15-validated class at pair granularity:
//   stage(pair p+1 into other buffer) -> compute(2 tiles of pair p) -> vmcnt(0)
//   -> barrier.
// Barrier count halves (the R15 lever, applied once more). All per-tile address and
// swizzle math byte-identical. No setprio (R16: lockstep waves -> m190-class null).
__global__ __launch_bounds__(512) void attn(const __hip_bfloat16* __restrict__ Qh,
                                            const __hip_bfloat16* __restrict__ Kh,
                                            const __hip_bfloat16* __restrict__ Vt,
                                            const int* __restrict__ vlens,
                                            __hip_bfloat16* __restrict__ O,
                                            int* __restrict__ ctr) {
  const int t = threadIdx.x, lane = t & 63, w = t >> 6;  // w in 0..7
  const int wq = w & 3, up = w >> 2;  // sub-wave row group, unit half
  const int q = lane & 31;   // q-row owned by this lane
  const int hh = lane >> 5;  // half-wave

  // heavy-first batch order via stable 4-element sorting network
  int va = vlens[0], vb = vlens[1], vc = vlens[2], vd = vlens[3];
  int ia = 0, ib = 1, ic = 2, id_ = 3;
  {
    int tv, ti;
#define CSWAP(x, xi, y, yi) \
    if (y > x) { tv = x; x = y; y = tv; ti = xi; xi = yi; yi = ti; }
    CSWAP(va, ia, vb, ib) CSWAP(vc, ic, vd, id_)
    CSWAP(va, ia, vc, ic) CSWAP(vb, ib, vd, id_)
    CSWAP(vb, ib, vc, ic)
#undef CSWAP
  }
  __shared__ int s_unit;
  // two pair-buffers; each holds 2 tiles of [K 64x64 (8KB) | V^T 64x64 (8KB)]
  __shared__ __align__(16) __hip_bfloat16 smem[2][16384];  // 64 KB

  while (true) {
    if (t == 0) s_unit = atomicAdd(ctr, 1);
    __syncthreads();  // broadcast unit; also fences last unit's LDS use vs re-staging
    const int u = s_unit;
    if (u >= 512) break;
    const int rank = u >> 7;            // 128 units per batch rank
    const int b = (rank == 0) ? ia : (rank == 1) ? ib : (rank == 2) ? ic : id_;
    const int vlen = (rank == 0) ? va : (rank == 1) ? vb : (rank == 2) ? vc : vd;
    const int r = u & 127;
    const int h = r & 15, qtp = r >> 4;  // qtp in 0..7: 256-row q-pair
    const int bh = b * 16 + h;

    const __hip_bfloat16* Qb = Qh + (size_t)bh * S_ * HD_;
    const __hip_bfloat16* Kb = Kh + (size_t)bh * S_ * HD_;
    const __hip_bfloat16* Vb = Vt + (size_t)bh * HD_ * S_;

    const int qrow = qtp * 256 + up * 128 + wq * 32 + q;
    bf16x8 qf[4];
#pragma unroll
    for (int kk = 0; kk < 4; ++kk)
      qf[kk] = *reinterpret_cast<const bf16x8*>(Qb + (size_t)qrow * HD_ + kk * 16 + hh * 8);

    f32x16 accT[2] = {};  // O^T: accT[ctd] reg r -> d = ctd*32+(r&3)+8*(r>>2)+4*hh, col=q
    float l_half = 0.f;

    const int srow = lane >> 3;  // 0..7
    const int sg = lane & 7;     // 16B granule in 128B row
    const float maskv = (vlen == 0) ? 0.f : NEGV;
    const int kv_end = (vlen == 0) ? S_ : min(S_, (vlen + 63) & ~63);
    const int nt = kv_end >> 6;
    const int npair = (nt + 1) >> 1;

    // stage a PAIR of tiles into buffer buf; wave w stages rows [w*8, w*8+8) of
    // each tile's K and V^T -> up to 4 gld_lds per wave per pair.
    auto stagePair = [&](int buf, int pt) {
      int rr = w * 8 + srow;
      int gs = sg ^ (rr & 7);
#pragma unroll
      for (int half = 0; half < 2; ++half) {
        int tile = 2 * pt + half;
        if (tile >= nt) break;  // odd-nt tail (wave-uniform)
        int kv = tile * 64;
        gld_lds16(Kb + (size_t)(kv + rr) * HD_ + gs * 8,
                  smem[buf] + half * 8192 + (w * 8) * 64);
        gld_lds16(Vb + (size_t)rr * S_ + kv + gs * 8,
                  smem[buf] + half * 8192 + 4096 + (w * 8) * 64);
      }
    };

    stagePair(0, 0);
    asm volatile("s_waitcnt vmcnt(0)" ::: "memory");
    __syncthreads();
    int cur = 0;

    for (int p = 0; p < npair; ++p) {
      if (p + 1 < npair) stagePair(cur ^ 1, p + 1);  // prefetch overlaps 2-tile compute

#pragma unroll
      for (int half = 0; half < 2; ++half) {
        int tile = 2 * p + half;
        if (tile >= nt) break;  // odd-nt tail (wave-uniform)
        const __hip_bfloat16* Ks = smem[cur] + half * 8192;
        const __hip_bfloat16* Vs = Ks + 4096;

        // S^T tiles (log2-domain scores; Q carried the 0.125*log2e scale)
        f32x16 sc[2];
#pragma unroll
        for (int ct = 0; ct < 2; ++ct) {
          f32x16 a = {};
#pragma unroll
          for (int kk = 0; kk < 4; ++kk) {
            int row = ct * 32 + q;
            bf16x8 kf = *reinterpret_cast<const bf16x8*>(
                Ks + row * 64 + (((kk * 2 + hh) ^ (row & 7)) << 3));
            a = mfma32(kf, qf[kk], a);
          }
          sc[ct] = a;
        }

        // padding mask (boundary tile only; wave-uniform branch)
        int kv = tile * 64;
        if (kv + 64 > vlen) {
#pragma unroll
          for (int ct = 0; ct < 2; ++ct)
#pragma unroll
            for (int rr = 0; rr < 16; ++rr) {
              int j = kv + ct * 32 + (rr & 3) + 8 * (rr >> 2) + 4 * hh;
              if (j >= vlen) sc[ct][rr] = maskv;
            }
        }

        // exp (raw v_exp_f32) + bit-trick pack into 16 bf16x2 words
        uint wlo[8], whi[8];
        float rs = 0.f;
#pragma unroll
        for (int a2 = 0; a2 < 8; ++a2) {
          float p0 = exp2_hw(sc[a2 >> 2][(a2 & 3) * 4 + 0]);
          float p1 = exp2_hw(sc[a2 >> 2][(a2 & 3) * 4 + 1]);
          float p2 = exp2_hw(sc[a2 >> 2][(a2 & 3) * 4 + 2]);
          float p3 = exp2_hw(sc[a2 >> 2][(a2 & 3) * 4 + 3]);
          rs += (p0 + p1) + (p2 + p3);
          wlo[a2] = pk2bf(p0, p1);
          whi[a2] = pk2bf(p2, p3);
        }
        l_half += rs;

        // PV: B-frag = P[q][kk*16 + hh*8 + i]; half-wave exchange fills missing slots
#pragma unroll
        for (int kk = 0; kk < 4; ++kk) {
          uint glo = wlo[2 * kk], ghi = whi[2 * kk];
          uint flo = wlo[2 * kk + 1], fhi = whi[2 * kk + 1];
          uint slo = hh ? glo : flo, shi = hh ? ghi : fhi;
          uint rlo = __shfl_xor(slo, 32), rhi = __shfl_xor(shi, 32);
          union { uint u[4]; bf16x8 v; } pf;
          pf.u[0] = hh ? rlo : glo;
          pf.u[1] = hh ? rhi : ghi;
          pf.u[2] = hh ? flo : rlo;
          pf.u[3] = hh ? fhi : rhi;
#pragma unroll
          for (int ctd = 0; ctd < 2; ++ctd) {
            int vr = ctd * 32 + q;
            bf16x8 vf = *reinterpret_cast<const bf16x8*>(
                Vs + vr * 64 + (((kk * 2 + hh) ^ (vr & 7)) << 3));
            accT[ctd] = mfma32(vf, pf.v, accT[ctd]);
          }
        }
      }

      // drain own prefetch (issued before the 2-tile compute, so HBM latency is
      // covered) + barrier: all waves' stage(p+1) writes visible, buffer safe.
      asm volatile("s_waitcnt vmcnt(0)" ::: "memory");
      __syncthreads();
      cur ^= 1;
    }

    // epilogue: O^T -> O via per-wave LDS transpose (same-wave ordering, no barrier).
    // 8 waves x 4KB = 32KB fits pair buffer 0 (loop-end barrier protects it).
    float l_tot = l_half + __shfl_xor(l_half, 32);
    float inv = 1.f / l_tot;
    __hip_bfloat16* Ot = smem[0] + w * 2048;  // [32 q][64 d], 8B-granule swizzle
#pragma unroll
    for (int ctd = 0; ctd < 2; ++ctd)
#pragma unroll
      for (int a2 = 0; a2 < 4; ++a2) {
        uint2 o;
        o.x = pk2bf(accT[ctd][a2 * 4 + 0] * inv, accT[ctd][a2 * 4 + 1] * inv);
        o.y = pk2bf(accT[ctd][a2 * 4 + 2] * inv, accT[ctd][a2 * 4 + 3] * inv);
        int gs8 = (ctd * 8 + a2 * 2 + hh) ^ ((q & 7) << 1);
        *reinterpret_cast<uint2*>(Ot + q * 64 + gs8 * 4) = o;
      }
#pragma unroll
    for (int rr = 0; rr < 4; ++rr) {
      int row = rr * 8 + (lane >> 3);  // q-row within wave tile
      int c16 = lane & 7;              // 16B chunk of d
      float4 v4 = *reinterpret_cast<const float4*>(
          Ot + row * 64 + (((c16 * 2) ^ ((row & 7) << 1)) << 2));
      int s = qtp * 256 + up * 128 + wq * 32 + row;
      *reinterpret_cast<float4*>(O + ((size_t)b * S_ + s) * D_ + h * HD_ + c16 * 8) = v4;
    }
  }
}

extern "C" void kernel_launch(void* const* d_in, const int* in_sizes, int n_in,
                              void* d_out, int out_size, void* d_ws, size_t ws_size,
                              hipStream_t stream) {
  const float* Xq = (const float*)d_in[0];
  const float* Xk = (const float*)d_in[1];
  const float* Xv = (const float*)d_in[2];
  const int* vl = (const int*)d_in[3];
  const float* Wq = (const float*)d_in[4];
  const float* Wk = (const float*)d_in[5];
  const float* Wv = (const float*)d_in[6];
  const float* Wo = (const float*)d_in[7];
  float* out = (float*)d_out;

  char* ws = (char*)d_ws;
  const size_t XB = (size_t)M_ * D_ * 2;   // 16 MB bf16 [8192][1024]
  const size_t WB = (size_t)D_ * D_ * 2;   // 2 MB bf16 [1024][1024]
  __hip_bfloat16* xq = (__hip_bfloat16*)(ws);                    // Xq bf16, later Obuf
  __hip_bfloat16* xk = (__hip_bfloat16*)(ws + XB);               // Xk bf16, later ctr
  __hip_bfloat16* xv = (__hip_bfloat16*)(ws + 2 * XB);           // Xv bf16
  __hip_bfloat16* wtq = (__hip_bfloat16*)(ws + 3 * XB);          // wtq..wto contiguous
  __hip_bfloat16* wtk = (__hip_bfloat16*)(ws + 3 * XB + WB);
  __hip_bfloat16* wtv = (__hip_bfloat16*)(ws + 3 * XB + 2 * WB);
  __hip_bfloat16* wto = (__hip_bfloat16*)(ws + 3 * XB + 3 * WB);
  __hip_bfloat16* Qh = (__hip_bfloat16*)(ws + 3 * XB + 4 * WB);      // [B][H][S][HD]
  __hip_bfloat16* Kh = (__hip_bfloat16*)(ws + 4 * XB + 4 * WB);      // [B][H][S][HD]
  __hip_bfloat16* Vh = (__hip_bfloat16*)(ws + 5 * XB + 4 * WB);      // [B][H][HD][S]
  __hip_bfloat16* Obuf = xq;      // alias: xq dead after the Q projection GEMM
  int* ctr = (int*)xk;            // alias: xk dead after the K projection GEMM

  convert_wt4<<<dim3(32, 32, 4), dim3(32, 8), 0, stream>>>(Wq, Wk, Wv, Wo, wtq);

  const int n4 = M_ * D_ / 4;
  convert_x3<<<dim3(n4 / 256, 3), 256, 0, stream>>>(Xq, Xk, Xv, xq, xk, xv, n4, vl);

  dim3 gg(M_ / 128, D_ / 128);
  gemm_bt<0><<<gg, 256, 0, stream>>>(xq, wtq, Qh, nullptr, CEXP);  // Q carries softmax scale
  gemm_bt<0><<<gg, 256, 0, stream>>>(xk, wtk, Kh, vl, 1.0f);
  gemm_bt<1><<<gg, 256, 0, stream>>>(xv, wtv, Vh, vl, 1.0f);

  hipMemsetAsync(ctr, 0, sizeof(int), stream);  // reset work-stealing counter
  attn<<<dim3(512), 512, 0, stream>>>(Qh, Kh, Vh, vl, Obuf, ctr);
  gemm_bt<2><<<gg, 256, 0, stream>>>(Obuf, wto, out, nullptr, 1.0f);
}

// Round 20
// 178.386 us; speedup vs baseline: 1.1791x; 1.0914x over previous
//
#include <hip/hip_runtime.h>
#include <hip/hip_bf16.h>

// Problem constants
#define B_ 4
#define S_ 2048
#define D_ 1024
#define H_ 16
#define HD_ 64
#define M_ 8192           // B*S
#define NEGV -1000000.0f
#define CEXP 0.18033688011112042f   // (1/sqrt(HD)) * log2(e) — folded into Q projection

typedef __attribute__((ext_vector_type(8))) __bf16 bf16x8;
typedef __attribute__((ext_vector_type(4))) float f32x4;
typedef __attribute__((ext_vector_type(16))) float f32x16;

__device__ __forceinline__ f32x4 mfma16(bf16x8 a, bf16x8 b, f32x4 c) {
  return __builtin_amdgcn_mfma_f32_16x16x32_bf16(a, b, c, 0, 0, 0);
}
__device__ __forceinline__ f32x16 mfma32(bf16x8 a, bf16x8 b, f32x16 c) {
  return __builtin_amdgcn_mfma_f32_32x32x16_bf16(a, b, c, 0, 0, 0);
}

// raw v_exp_f32 (exp2f without -ffast-math is a guarded libm sequence)
#if __has_builtin(__builtin_amdgcn_exp2f)
__device__ __forceinline__ float exp2_hw(float x) { return __builtin_amdgcn_exp2f(x); }
#else
__device__ __forceinline__ float exp2_hw(float x) {
  float r;
  asm volatile("v_exp_f32 %0, %1" : "=v"(r) : "v"(x));
  return r;
}
#endif

// Branchless RNE fp32->bf16 (exact for all finite values; no NaNs in this pipeline).
__device__ __forceinline__ unsigned bf16rz(float x) {
  unsigned u = __float_as_uint(x);
  return (u + 0x7FFFu + ((u >> 16) & 1u)) >> 16;
}
// pack two floats -> bf16x2 word (lo = a, hi = b)
__device__ __forceinline__ unsigned pk2bf(float a, float b) {
  unsigned ua = __float_as_uint(a), ub = __float_as_uint(b);
  ua = ua + 0x7FFFu + ((ua >> 16) & 1u);
  ub = ub + 0x7FFFu + ((ub >> 16) & 1u);
  return (ua >> 16) | (ub & 0xFFFF0000u);
}

// async global->LDS, 16B per lane. LDS dest is wave-uniform base (HW adds lane*16).
__device__ __forceinline__ void gld_lds16(const __hip_bfloat16* g, __hip_bfloat16* l) {
  __builtin_amdgcn_global_load_lds(
      (const __attribute__((address_space(1))) void*)g,
      (__attribute__((address_space(3))) void*)l, 16, 0, 0);
}

// ---------------- fp32 -> bf16 convert, all three X tensors in one launch -------------
__global__ __launch_bounds__(256) void convert_x3(const float* __restrict__ Xq,
                                                  const float* __restrict__ Xk,
                                                  const float* __restrict__ Xv,
                                                  __hip_bfloat16* __restrict__ Yq,
                                                  __hip_bfloat16* __restrict__ Yk,
                                                  __hip_bfloat16* __restrict__ Yv,
                                                  int n4, const int* __restrict__ vl) {
  const int z = blockIdx.y;
  const float* X = (z == 0) ? Xq : (z == 1) ? Xk : Xv;
  __hip_bfloat16* Y = (z == 0) ? Yq : (z == 1) ? Yk : Yv;
  int i = blockIdx.x * blockDim.x + threadIdx.x;
  if (i >= n4) return;
  if (z) {
    int gm = i >> 8;  // 256 float4 per 1024-wide row
    int vlen = vl[gm >> 11];
    if (vlen > 0 && (gm & 2047) >= ((vlen + 63) & ~63)) return;
  }
  float4 v = reinterpret_cast<const float4*>(X)[i];
  uint2 o;
  o.x = pk2bf(v.x, v.y);
  o.y = pk2bf(v.z, v.w);
  reinterpret_cast<uint2*>(Y)[i] = o;
}

// ---------------- 4x W[1024][1024] fp32 -> W^T bf16 (fused via blockIdx.z) -----------
__global__ __launch_bounds__(256) void convert_wt4(const float* __restrict__ W0,
                                                   const float* __restrict__ W1,
                                                   const float* __restrict__ W2,
                                                   const float* __restrict__ W3,
                                                   __hip_bfloat16* __restrict__ WtBase) {
  const int z = blockIdx.z;
  const float* W = (z == 0) ? W0 : (z == 1) ? W1 : (z == 2) ? W2 : W3;
  __hip_bfloat16* Wt = WtBase + (size_t)z * D_ * D_;
  __shared__ float tile[32][33];
  int c0 = blockIdx.x * 32, r0 = blockIdx.y * 32;
  int tx = threadIdx.x, ty = threadIdx.y;
#pragma unroll
  for (int rr = ty; rr < 32; rr += 8)
    tile[rr][tx] = W[(size_t)(r0 + rr) * D_ + c0 + tx];
  __syncthreads();
#pragma unroll
  for (int rr = ty; rr < 32; rr += 8)
    reinterpret_cast<unsigned short*>(Wt)[(size_t)(c0 + rr) * D_ + r0 + tx] =
        (unsigned short)bf16rz(tile[tx][rr]);
}

// ---------------- GEMM: C[M,N] = A[M,K] * Bt[N,K]^T  (bf16 in, templated epilogue) ----
// BK=64, XOR-swizzled LDS (T2), double-buffered 2-phase schedule (R9-R19-validated).
// LDS invariant: LDS[row][g] = global[row][g ^ (row&7)] (16B granules, involution).
// SEPARATE launches per projection (R16's z-fused dispatch broke the per-XCD
// {A-panel + W} L2 working set and regressed).
template <int EPI>
__global__ __launch_bounds__(256) void gemm_bt(const __hip_bfloat16* __restrict__ A,
                                               const __hip_bfloat16* __restrict__ Bt,
                                               void* __restrict__ Cout,
                                               const int* __restrict__ vskip,
                                               float cscale) {
  int id = blockIdx.y * gridDim.x + blockIdx.x;
  int cpx = (gridDim.x * gridDim.y) >> 3;
  int nid = (id & 7) * cpx + (id >> 3);
  const int m0 = (nid >> 3) * 128, n0 = (nid & 7) * 128;
  if (vskip) {
    int vlen = vskip[m0 >> 11];
    if (vlen > 0 && (m0 & 2047) >= ((vlen + 63) & ~63)) return;
  }
  const int t = threadIdx.x, lane = t & 63, wid = t >> 6;
  const int lc = lane & 15, g = lane >> 4;
  const int srow8 = lane >> 3, sg8 = lane & 7;
  __shared__ __align__(16) __hip_bfloat16 smem[2][2][128 * 64];  // [buf][A/B][tile] 64KB
  f32x4 acc[4][4] = {};
  const int wm = (wid & 1) * 64, wn = (wid >> 1) * 64;

  auto stage = [&](int buf, int k0) {
#pragma unroll
    for (int c = 0; c < 4; ++c) {
      int ci = c * 4 + wid;              // 1KB chunk index (8 rows)
      int row = ci * 8 + srow8;          // this lane's source row
      int sg = sg8 ^ (row & 7);          // inverse-swizzled source granule
      gld_lds16(A + (size_t)(m0 + row) * D_ + k0 + sg * 8, &smem[buf][0][ci * 512]);
      gld_lds16(Bt + (size_t)(n0 + row) * D_ + k0 + sg * 8, &smem[buf][1][ci * 512]);
    }
  };

  stage(0, 0);
  asm volatile("s_waitcnt vmcnt(0)" ::: "memory");
  __syncthreads();
  int cur = 0;

  for (int kt = 0; kt < D_ / 64; ++kt) {
    if (kt + 1 < D_ / 64) stage(cur ^ 1, (kt + 1) * 64);  // prefetch overlaps compute
    const __hip_bfloat16* As = smem[cur][0];
    const __hip_bfloat16* Bs = smem[cur][1];
#pragma unroll
    for (int kh = 0; kh < 2; ++kh) {  // two K=32 halves of the K=64 tile
      bf16x8 af[4], bf[4];
#pragma unroll
      for (int mi = 0; mi < 4; ++mi) {
        int r = wm + mi * 16 + lc;
        af[mi] = *reinterpret_cast<const bf16x8*>(
            As + r * 64 + (((kh * 4 + g) ^ (r & 7)) << 3));
        int rn = wn + mi * 16 + lc;
        bf[mi] = *reinterpret_cast<const bf16x8*>(
            Bs + rn * 64 + (((kh * 4 + g) ^ (rn & 7)) << 3));
      }
#pragma unroll
      for (int mi = 0; mi < 4; ++mi)
#pragma unroll
        for (int ni = 0; ni < 4; ++ni)
          acc[mi][ni] = mfma16(af[mi], bf[ni], acc[mi][ni]);
    }
    asm volatile("s_waitcnt vmcnt(0)" ::: "memory");
    __syncthreads();
    cur ^= 1;
  }

#pragma unroll
  for (int mi = 0; mi < 4; ++mi) {
#pragma unroll
    for (int ni = 0; ni < 4; ++ni) {
#pragma unroll
      for (int i = 0; i < 4; ++i) {
        int gm = m0 + wm + mi * 16 + g * 4 + i;
        int gn = n0 + wn + ni * 16 + lc;
        float val = acc[mi][ni][i] * cscale;
        if constexpr (EPI == 0) {
          int b = gm >> 11, s = gm & 2047, h = gn >> 6, d = gn & 63;
          reinterpret_cast<unsigned short*>(
              Cout)[(((size_t)(b * H_ + h) * S_ + s) << 6) + d] =
              (unsigned short)bf16rz(val);
        } else if constexpr (EPI == 1) {
          int b = gm >> 11, s = gm & 2047, h = gn >> 6, d = gn & 63;
          reinterpret_cast<unsigned short*>(
              Cout)[(((size_t)(b * H_ + h) * HD_ + d) << 11) + s] =
              (unsigned short)bf16rz(val);
        } else {
          ((float*)Cout)[(size_t)gm * D_ + gn] = val;
        }
      }
    }
  }
}

// ---------------- Flash attention: 8-wave blocks, 2 KV tiles per barrier step ---------
// R19 body verbatim. Scheduling change only: units = 512 = grid and all blocks are
// co-resident (66KB LDS -> exactly 2 blocks/CU x 256 = 512), so work stealing was
// degenerate (1 unit/block) and dispatch order irrelevant. Static u = blockIdx.x:
// drops the atomic, the s_unit broadcast barrier, the heavy-first sort, the loop
// re-entry barrier, and the ctr memset dispatch.
__global__ __launch_bounds__(512) void attn(const __hip_bfloat16* __restrict__ Qh,
                                            const __hip_bfloat16* __restrict__ Kh,
                                            const __hip_bfloat16* __restrict__ Vt,
                                            const int* __restrict__ vlens,
                                            __hip_bfloat16* __restrict__ O) {
  const int t = threadIdx.x, lane = t & 63, w = t >> 6;  // w in 0..7
  const int wq = w & 3, up = w >> 2;  // sub-wave row group, unit half
  const int q = lane & 31;   // q-row owned by this lane
  const int hh = lane >> 5;  // half-wave

  const int u = blockIdx.x;           // 512 units, all resident from t=0
  const int b = u >> 7;               // 128 units per batch
  const int vlen = vlens[b];
  const int r = u & 127;
  const int h = r & 15, qtp = r >> 4; // qtp in 0..7: 256-row q-pair
  const int bh = b * 16 + h;

  // two pair-buffers; each holds 2 tiles of [K 64x64 (8KB) | V^T 64x64 (8KB)]
  __shared__ __align__(16) __hip_bfloat16 smem[2][16384];  // 64 KB

  const __hip_bfloat16* Qb = Qh + (size_t)bh * S_ * HD_;
  const __hip_bfloat16* Kb = Kh + (size_t)bh * S_ * HD_;
  const __hip_bfloat16* Vb = Vt + (size_t)bh * HD_ * S_;

  const int qrow = qtp * 256 + up * 128 + wq * 32 + q;
  bf16x8 qf[4];
#pragma unroll
  for (int kk = 0; kk < 4; ++kk)
    qf[kk] = *reinterpret_cast<const bf16x8*>(Qb + (size_t)qrow * HD_ + kk * 16 + hh * 8);

  f32x16 accT[2] = {};  // O^T: accT[ctd] reg r -> d = ctd*32+(r&3)+8*(r>>2)+4*hh, col=q
  float l_half = 0.f;

  const int srow = lane >> 3;  // 0..7
  const int sg = lane & 7;     // 16B granule in 128B row
  const float maskv = (vlen == 0) ? 0.f : NEGV;
  const int kv_end = (vlen == 0) ? S_ : min(S_, (vlen + 63) & ~63);
  const int nt = kv_end >> 6;
  const int npair = (nt + 1) >> 1;

  // stage a PAIR of tiles into buffer buf; wave w stages rows [w*8, w*8+8) of
  // each tile's K and V^T -> up to 4 gld_lds per wave per pair.
  auto stagePair = [&](int buf, int pt) {
    int rr = w * 8 + srow;
    int gs = sg ^ (rr & 7);
#pragma unroll
    for (int half = 0; half < 2; ++half) {
      int tile = 2 * pt + half;
      if (tile >= nt) break;  // odd-nt tail (wave-uniform)
      int kv = tile * 64;
      gld_lds16(Kb + (size_t)(kv + rr) * HD_ + gs * 8,
                smem[buf] + half * 8192 + (w * 8) * 64);
      gld_lds16(Vb + (size_t)rr * S_ + kv + gs * 8,
                smem[buf] + half * 8192 + 4096 + (w * 8) * 64);
    }
  };

  stagePair(0, 0);
  asm volatile("s_waitcnt vmcnt(0)" ::: "memory");
  __syncthreads();
  int cur = 0;

  for (int p = 0; p < npair; ++p) {
    if (p + 1 < npair) stagePair(cur ^ 1, p + 1);  // prefetch overlaps 2-tile compute

#pragma unroll
    for (int half = 0; half < 2; ++half) {
      int tile = 2 * p + half;
      if (tile >= nt) break;  // odd-nt tail (wave-uniform)
      const __hip_bfloat16* Ks = smem[cur] + half * 8192;
      const __hip_bfloat16* Vs = Ks + 4096;

      // S^T tiles (log2-domain scores; Q carried the 0.125*log2e scale)
      f32x16 sc[2];
#pragma unroll
      for (int ct = 0; ct < 2; ++ct) {
        f32x16 a = {};
#pragma unroll
        for (int kk = 0; kk < 4; ++kk) {
          int row = ct * 32 + q;
          bf16x8 kf = *reinterpret_cast<const bf16x8*>(
              Ks + row * 64 + (((kk * 2 + hh) ^ (row & 7)) << 3));
          a = mfma32(kf, qf[kk], a);
        }
        sc[ct] = a;
      }

      // padding mask (boundary tile only; wave-uniform branch)
      int kv = tile * 64;
      if (kv + 64 > vlen) {
#pragma unroll
        for (int ct = 0; ct < 2; ++ct)
#pragma unroll
          for (int rr = 0; rr < 16; ++rr) {
            int j = kv + ct * 32 + (rr & 3) + 8 * (rr >> 2) + 4 * hh;
            if (j >= vlen) sc[ct][rr] = maskv;
          }
      }

      // exp (raw v_exp_f32) + bit-trick pack into 16 bf16x2 words
      uint wlo[8], whi[8];
      float rs = 0.f;
#pragma unroll
      for (int a2 = 0; a2 < 8; ++a2) {
        float p0 = exp2_hw(sc[a2 >> 2][(a2 & 3) * 4 + 0]);
        float p1 = exp2_hw(sc[a2 >> 2][(a2 & 3) * 4 + 1]);
        float p2 = exp2_hw(sc[a2 >> 2][(a2 & 3) * 4 + 2]);
        float p3 = exp2_hw(sc[a2 >> 2][(a2 & 3) * 4 + 3]);
        rs += (p0 + p1) + (p2 + p3);
        wlo[a2] = pk2bf(p0, p1);
        whi[a2] = pk2bf(p2, p3);
      }
      l_half += rs;

      // PV: B-frag = P[q][kk*16 + hh*8 + i]; half-wave exchange fills missing slots
#pragma unroll
      for (int kk = 0; kk < 4; ++kk) {
        uint glo = wlo[2 * kk], ghi = whi[2 * kk];
        uint flo = wlo[2 * kk + 1], fhi = whi[2 * kk + 1];
        uint slo = hh ? glo : flo, shi = hh ? ghi : fhi;
        uint rlo = __shfl_xor(slo, 32), rhi = __shfl_xor(shi, 32);
        union { uint u[4]; bf16x8 v; } pf;
        pf.u[0] = hh ? rlo : glo;
        pf.u[1] = hh ? rhi : ghi;
        pf.u[2] = hh ? flo : rlo;
        pf.u[3] = hh ? fhi : rhi;
#pragma unroll
        for (int ctd = 0; ctd < 2; ++ctd) {
          int vr = ctd * 32 + q;
          bf16x8 vf = *reinterpret_cast<const bf16x8*>(
              Vs + vr * 64 + (((kk * 2 + hh) ^ (vr & 7)) << 3));
          accT[ctd] = mfma32(vf, pf.v, accT[ctd]);
        }
      }
    }

    // drain own prefetch (issued before the 2-tile compute, so HBM latency is
    // covered) + barrier: all waves' stage(p+1) writes visible, buffer safe.
    asm volatile("s_waitcnt vmcnt(0)" ::: "memory");
    __syncthreads();
    cur ^= 1;
  }

  // epilogue: O^T -> O via per-wave LDS transpose (same-wave ordering, no barrier).
  // 8 waves x 4KB = 32KB fits pair buffer 0 (loop-end barrier protects it).
  float l_tot = l_half + __shfl_xor(l_half, 32);
  float inv = 1.f / l_tot;
  __hip_bfloat16* Ot = smem[0] + w * 2048;  // [32 q][64 d], 8B-granule swizzle
#pragma unroll
  for (int ctd = 0; ctd < 2; ++ctd)
#pragma unroll
    for (int a2 = 0; a2 < 4; ++a2) {
      uint2 o;
      o.x = pk2bf(accT[ctd][a2 * 4 + 0] * inv, accT[ctd][a2 * 4 + 1] * inv);
      o.y = pk2bf(accT[ctd][a2 * 4 + 2] * inv, accT[ctd][a2 * 4 + 3] * inv);
      int gs8 = (ctd * 8 + a2 * 2 + hh) ^ ((q & 7) << 1);
      *reinterpret_cast<uint2*>(Ot + q * 64 + gs8 * 4) = o;
    }
#pragma unroll
  for (int rr = 0; rr < 4; ++rr) {
    int row = rr * 8 + (lane >> 3);  // q-row within wave tile
    int c16 = lane & 7;              // 16B chunk of d
    float4 v4 = *reinterpret_cast<const float4*>(
        Ot + row * 64 + (((c16 * 2) ^ ((row & 7) << 1)) << 2));
    int s = qtp * 256 + up * 128 + wq * 32 + row;
    *reinterpret_cast<float4*>(O + ((size_t)b * S_ + s) * D_ + h * HD_ + c16 * 8) = v4;
  }
}

extern "C" void kernel_launch(void* const* d_in, const int* in_sizes, int n_in,
                              void* d_out, int out_size, void* d_ws, size_t ws_size,
                              hipStream_t stream) {
  const float* Xq = (const float*)d_in[0];
  const float* Xk = (const float*)d_in[1];
  const float* Xv = (const float*)d_in[2];
  const int* vl = (const int*)d_in[3];
  const float* Wq = (const float*)d_in[4];
  const float* Wk = (const float*)d_in[5];
  const float* Wv = (const float*)d_in[6];
  const float* Wo = (const float*)d_in[7];
  float* out = (float*)d_out;

  char* ws = (char*)d_ws;
  const size_t XB = (size_t)M_ * D_ * 2;   // 16 MB bf16 [8192][1024]
  const size_t WB = (size_t)D_ * D_ * 2;   // 2 MB bf16 [1024][1024]
  __hip_bfloat16* xq = (__hip_bfloat16*)(ws);                    // Xq bf16, later Obuf
  __hip_bfloat16* xk = (__hip_bfloat16*)(ws + XB);               // Xk bf16
  __hip_bfloat16* xv = (__hip_bfloat16*)(ws + 2 * XB);           // Xv bf16
  __hip_bfloat16* wtq = (__hip_bfloat16*)(ws + 3 * XB);          // wtq..wto contiguous
  __hip_bfloat16* wtk = (__hip_bfloat16*)(ws + 3 * XB + WB);
  __hip_bfloat16* wtv = (__hip_bfloat16*)(ws + 3 * XB + 2 * WB);
  __hip_bfloat16* wto = (__hip_bfloat16*)(ws + 3 * XB + 3 * WB);
  __hip_bfloat16* Qh = (__hip_bfloat16*)(ws + 3 * XB + 4 * WB);      // [B][H][S][HD]
  __hip_bfloat16* Kh = (__hip_bfloat16*)(ws + 4 * XB + 4 * WB);      // [B][H][S][HD]
  __hip_bfloat16* Vh = (__hip_bfloat16*)(ws + 5 * XB + 4 * WB);      // [B][H][HD][S]
  __hip_bfloat16* Obuf = xq;      // alias: xq dead after the Q projection GEMM

  convert_wt4<<<dim3(32, 32, 4), dim3(32, 8), 0, stream>>>(Wq, Wk, Wv, Wo, wtq);

  const int n4 = M_ * D_ / 4;
  convert_x3<<<dim3(n4 / 256, 3), 256, 0, stream>>>(Xq, Xk, Xv, xq, xk, xv, n4, vl);

  dim3 gg(M_ / 128, D_ / 128);
  gemm_bt<0><<<gg, 256, 0, stream>>>(xq, wtq, Qh, nullptr, CEXP);  // Q carries softmax scale
  gemm_bt<0><<<gg, 256, 0, stream>>>(xk, wtk, Kh, vl, 1.0f);
  gemm_bt<1><<<gg, 256, 0, stream>>>(xv, wtv, Vh, vl, 1.0f);

  attn<<<dim3(512), 512, 0, stream>>>(Qh, Kh, Vh, vl, Obuf);
  gemm_bt<2><<<gg, 256, 0, stream>>>(Obuf, wto, out, nullptr, 1.0f);
}